// Round 1
// baseline (454.071 us; speedup 1.0000x reference)
//
#include <hip/hip_runtime.h>

typedef unsigned short u16;
typedef unsigned int u32;
typedef __attribute__((ext_vector_type(8))) short bf16x8;
typedef __attribute__((ext_vector_type(4))) float f32x4;
typedef __attribute__((ext_vector_type(2))) float f32x2;
typedef __attribute__((ext_vector_type(8))) u16 u16x8;
typedef __attribute__((ext_vector_type(4))) u16 u16x4;
typedef __attribute__((ext_vector_type(2))) u16 u16x2;
typedef __attribute__((ext_vector_type(2))) u32 u32x2;

#define DIM 128

__device__ __forceinline__ u32 f2bf(float f){
  u32 x = __float_as_uint(f);
  return (x + 0x7fffu + ((x >> 16) & 1u)) >> 16;
}
__device__ __forceinline__ float bf2f(u16 u){
  return __uint_as_float(((u32)u) << 16);
}

// ---------------- prep: cast x -> bf16, zero-pad to tile rows ----------------
__global__ __launch_bounds__(256) void cast_x_kernel(const float* __restrict__ x,
                                                     u16* __restrict__ xb, int N, int rows){
  int id = blockIdx.x * 256 + threadIdx.x;   // 4 elements per thread
  int total4 = rows * (DIM / 4);
  if (id >= total4) return;
  int el = id * 4;
  int node = el >> 7;
  u32x2 pk;
  if (node < N){
    f32x4 v = *(const f32x4*)(x + el);
    pk.x = f2bf(v.x) | (f2bf(v.y) << 16);
    pk.y = f2bf(v.z) | (f2bf(v.w) << 16);
  } else { pk.x = 0u; pk.y = 0u; }
  *(u32x2*)(xb + el) = pk;
}

// ---------------- prep: build transposed concat weights (bf16) + bias --------
// Column layout (global col c, ncol = (3T+1)*128):
//   c in [0, 2T*128): per type t (256 cols each): even -> Wq[t][:,j], odd -> Wv[t][:,j]
//   c in [2T*128, 3T*128): k blocks: Wk[t][:,j]
//   c in [3T*128, ...): mean_t Ws[t][:,j]
__global__ __launch_bounds__(256) void build_w_kernel(
    const float* __restrict__ Wk, const float* __restrict__ bk,
    const float* __restrict__ Wq, const float* __restrict__ bq,
    const float* __restrict__ Wv, const float* __restrict__ bv,
    const float* __restrict__ Ws, const float* __restrict__ bb,
    u16* __restrict__ WcatT, float* __restrict__ biascat, int T){
  int id = blockIdx.x * 256 + threadIdx.x;
  int total = (3 * T + 1) * DIM * DIM;
  if (id >= total) return;
  int kk = id & (DIM - 1);
  int c  = id >> 7;
  int qvspan = 2 * T * DIM;
  float wv, bvv;
  if (c < qvspan){
    int t = c >> 8;            // 256 cols per type
    int w = c & 255;
    int j = w >> 1;
    if ((w & 1) == 0){ wv = Wq[(t*DIM + kk)*DIM + j]; bvv = bq[t*DIM + j]; }
    else             { wv = Wv[(t*DIM + kk)*DIM + j]; bvv = bv[t*DIM + j]; }
  } else if (c < qvspan + T * DIM){
    int t = (c - qvspan) >> 7;
    int j = (c - qvspan) & (DIM - 1);
    wv = Wk[(t*DIM + kk)*DIM + j]; bvv = bk[t*DIM + j];
  } else {
    int j = c - 3 * T * DIM;
    float s = 0.f, sb = 0.f;
    for (int t = 0; t < T; ++t){ s += Ws[(t*DIM + kk)*DIM + j]; sb += bb[t*DIM + j]; }
    wv = s / (float)T; bvv = sb / (float)T;
  }
  WcatT[(size_t)c * DIM + kk] = (u16)f2bf(wv);
  if (kk == 0) biascat[c] = bvv;
}

// ---------------- CSR build --------------------------------------------------
__global__ __launch_bounds__(256) void hist_kernel(const int* __restrict__ dst,
                                                   int* __restrict__ cnt, int E){
  int e = blockIdx.x * 256 + threadIdx.x;
  if (e < E) atomicAdd(&cnt[dst[e]], 1);
}

__global__ __launch_bounds__(1024) void scan_kernel(const int* __restrict__ cnt,
                                                    int* __restrict__ offs,
                                                    int* __restrict__ cursor, int n){
  __shared__ int sd[1024];
  __shared__ int carry;
  int tid = threadIdx.x;
  if (tid == 0) carry = 0;
  __syncthreads();
  for (int base = 0; base < n; base += 8192){
    int vals[8];
    int idx0 = base + tid * 8;
    int tot = 0;
#pragma unroll
    for (int j = 0; j < 8; ++j){
      int idx = idx0 + j;
      int v = (idx < n) ? cnt[idx] : 0;
      vals[j] = v; tot += v;
    }
    sd[tid] = tot;
    __syncthreads();
    for (int off = 1; off < 1024; off <<= 1){
      int add = 0;
      if (tid >= off) add = sd[tid - off];
      __syncthreads();
      sd[tid] += add;
      __syncthreads();
    }
    int carry_old = carry;
    int excl = carry_old + sd[tid] - tot;
#pragma unroll
    for (int j = 0; j < 8; ++j){
      int idx = idx0 + j;
      if (idx < n){ offs[idx] = excl; cursor[idx] = excl; }
      excl += vals[j];
    }
    __syncthreads();
    if (tid == 1023) carry = carry_old + sd[1023];
    __syncthreads();
  }
  if (tid == 0) offs[n] = carry;
}

__global__ __launch_bounds__(256) void scatter_kernel(const int* __restrict__ src,
                                                      const int* __restrict__ dst,
                                                      const int* __restrict__ et,
                                                      int* __restrict__ cursor,
                                                      int* __restrict__ packed, int E){
  int e = blockIdx.x * 256 + threadIdx.x;
  if (e >= E) return;
  int d = dst[e];
  int pos = atomicAdd(&cursor[d], 1);
  packed[pos] = (src[e] << 2) | (et[e] & 3);
}

// ---------------- batched MFMA GEMM: Y = xb @ Wcat + bias (bf16 out) ---------
// Computes D[n][m] via mfma(A=W^T fragment, B=x fragment):
//   C/D: col(=m) = lane&15, row(=n) = (lane>>4)*4 + reg   (guide §3, m89/m91)
#define LDSS 88   // LDS row stride (elements): 176B = 16B-aligned, 12-bank shift/row
__global__ __launch_bounds__(256) void gemm_kernel(const u16* __restrict__ xb,
                                                   const u16* __restrict__ WcatT,
                                                   const float* __restrict__ biascat,
                                                   u16* __restrict__ Y,
                                                   int N, int ncol){
  __shared__ u16 xt[128 * LDSS];
  __shared__ u16 wt[128 * LDSS];
  const int m0 = blockIdx.x * 128;
  const int n0 = blockIdx.y * 128;
  const int tid  = threadIdx.x;
  const int wave = tid >> 6;
  const int lane = tid & 63;
  const int l15  = lane & 15;
  const int quad = lane >> 4;
  const int wrow = wave * 32;

  f32x4 acc[2][8];
#pragma unroll
  for (int mt = 0; mt < 2; ++mt)
#pragma unroll
    for (int nt = 0; nt < 8; ++nt)
      acc[mt][nt] = (f32x4){0.f, 0.f, 0.f, 0.f};

  for (int kb = 0; kb < 2; ++kb){
    const int koff = kb * 64;
#pragma unroll
    for (int it = 0; it < 4; ++it){
      int id = it * 256 + tid;
      int r  = id >> 3;
      int c8 = (id & 7) * 8;
      *(u16x8*)&xt[r * LDSS + c8] = *(const u16x8*)&xb[(size_t)(m0 + r) * DIM + koff + c8];
      *(u16x8*)&wt[r * LDSS + c8] = *(const u16x8*)&WcatT[(size_t)(n0 + r) * DIM + koff + c8];
    }
    __syncthreads();
#pragma unroll
    for (int ks = 0; ks < 2; ++ks){
      const int kbase = ks * 32 + quad * 8;
      bf16x8 bfr[2], afr[8];
#pragma unroll
      for (int mt = 0; mt < 2; ++mt)
        bfr[mt] = *(const bf16x8*)&xt[(wrow + mt * 16 + l15) * LDSS + kbase];
#pragma unroll
      for (int nt = 0; nt < 8; ++nt)
        afr[nt] = *(const bf16x8*)&wt[(nt * 16 + l15) * LDSS + kbase];
#pragma unroll
      for (int nt = 0; nt < 8; ++nt)
#pragma unroll
        for (int mt = 0; mt < 2; ++mt)
          acc[mt][nt] = __builtin_amdgcn_mfma_f32_16x16x32_bf16(afr[nt], bfr[mt], acc[mt][nt], 0, 0, 0);
    }
    __syncthreads();
  }

  // epilogue: D element (row = n_local = quad*4+r, col = m_local = l15)
#pragma unroll
  for (int mt = 0; mt < 2; ++mt){
    int node = m0 + wrow + mt * 16 + l15;
    if (node >= N) continue;
    size_t rowbase = (size_t)node * ncol;
#pragma unroll
    for (int nt = 0; nt < 8; ++nt){
      int feat = n0 + nt * 16 + quad * 4;
      f32x4 b4 = *(const f32x4*)&biascat[feat];
      f32x4 v  = acc[mt][nt];
      u32 lo = f2bf(v.x + b4.x) | (f2bf(v.y + b4.y) << 16);
      u32 hi = f2bf(v.z + b4.z) | (f2bf(v.w + b4.w) << 16);
      u32x2 pk = {lo, hi};
      *(u32x2*)&Y[rowbase + feat] = pk;
    }
  }
}

// ---------------- aggregate + epilogue: one wave per dst node ----------------
__global__ __launch_bounds__(256) void agg_kernel(const u16* __restrict__ Y,
                                                  const int* __restrict__ offs,
                                                  const int* __restrict__ packed,
                                                  float* __restrict__ out,
                                                  int N, int T, float invT, int ncol){
  const int wave = threadIdx.x >> 6;
  const int lane = threadIdx.x & 63;
  const int i = blockIdx.x * 4 + wave;
  if (i >= N) return;

  const int kqoff = 2 * T * DIM;   // 1024
  const int soff  = 3 * T * DIM;   // 1536
  const u16* yr = Y + (size_t)i * ncol;
  const int c2 = lane * 2;

  u16x2 kw0 = *(const u16x2*)(yr + kqoff + 0 * DIM + c2);
  u16x2 kw1 = *(const u16x2*)(yr + kqoff + 1 * DIM + c2);
  u16x2 kw2 = *(const u16x2*)(yr + kqoff + 2 * DIM + c2);
  u16x2 kw3 = *(const u16x2*)(yr + kqoff + 3 * DIM + c2);
  float k0a = bf2f(kw0.x), k0b = bf2f(kw0.y);
  float k1a = bf2f(kw1.x), k1b = bf2f(kw1.y);
  float k2a = bf2f(kw2.x), k2b = bf2f(kw2.y);
  float k3a = bf2f(kw3.x), k3b = bf2f(kw3.y);
  u16x2 sw = *(const u16x2*)(yr + soff + c2);
  float s0 = bf2f(sw.x), s1 = bf2f(sw.y);

  float acc0 = 0.f, acc1 = 0.f;
  int e = offs[i], end = offs[i + 1];
  for (; e < end; ++e){
    int p = packed[e];
    int src = p >> 2;
    int t = p & 3;
    u16x4 qv = *(const u16x4*)(Y + (size_t)src * ncol + t * (2 * DIM) + lane * 4);
    float ka = (t == 0) ? k0a : (t == 1) ? k1a : (t == 2) ? k2a : k3a;
    float kb = (t == 0) ? k0b : (t == 1) ? k1b : (t == 2) ? k2b : k3b;
    float q0 = bf2f(qv.x), v0 = bf2f(qv.y);
    float q1 = bf2f(qv.z), v1 = bf2f(qv.w);
    float z0 = ka + q0, z1 = kb + q1;
    acc0 += v0 * __builtin_amdgcn_rcpf(1.f + __expf(-z0));
    acc1 += v1 * __builtin_amdgcn_rcpf(1.f + __expf(-z1));
  }
  f32x2 o = { invT * acc0 + s0, invT * acc1 + s1 };
  *(f32x2*)&out[(size_t)i * DIM + c2] = o;
}

// ---------------- launch -----------------------------------------------------
extern "C" void kernel_launch(void* const* d_in, const int* in_sizes, int n_in,
                              void* d_out, int out_size, void* d_ws, size_t ws_size,
                              hipStream_t stream){
  const float* x  = (const float*)d_in[0];
  const int*   ei = (const int*)d_in[1];
  const int*   et = (const int*)d_in[2];
  const float* Wk = (const float*)d_in[3];
  const float* bk = (const float*)d_in[4];
  const float* Wq = (const float*)d_in[5];
  const float* bq = (const float*)d_in[6];
  const float* Wv = (const float*)d_in[7];
  const float* bv = (const float*)d_in[8];
  const float* Ws = (const float*)d_in[9];
  const float* bb = (const float*)d_in[10];
  float* out = (float*)d_out;

  const int N = in_sizes[0] / DIM;
  const int E = in_sizes[2];
  const int T = in_sizes[3] / (DIM * DIM);
  const int NB = 3 * T + 1;
  const int ncol = NB * DIM;
  const int mtiles = (N + 127) / 128;
  const int rows = mtiles * 128;

  char* ws = (char*)d_ws;
  size_t off = 0;
  auto alloc = [&](size_t bytes) -> char* {
    char* p = ws + off;
    off = (off + bytes + 255) & ~(size_t)255;
    return p;
  };
  u16*   xb      = (u16*)alloc((size_t)rows * DIM * 2);
  u16*   WcatT   = (u16*)alloc((size_t)ncol * DIM * 2);
  float* biascat = (float*)alloc((size_t)ncol * 4);
  u16*   Y       = (u16*)alloc((size_t)N * ncol * 2);
  int*   cnt     = (int*)alloc((size_t)N * 4);
  int*   offs    = (int*)alloc((size_t)(N + 1) * 4);
  int*   cursor  = (int*)alloc((size_t)N * 4);
  int*   packed  = (int*)alloc((size_t)E * 4);
  (void)ws_size; (void)n_in; (void)out_size;

  const int* srcp = ei;
  const int* dstp = ei + E;

  hipMemsetAsync(cnt, 0, (size_t)N * 4, stream);
  cast_x_kernel<<<(rows * (DIM / 4) + 255) / 256, 256, 0, stream>>>(x, xb, N, rows);
  build_w_kernel<<<(ncol * DIM + 255) / 256, 256, 0, stream>>>(Wk, bk, Wq, bq, Wv, bv, Ws, bb, WcatT, biascat, T);
  hist_kernel<<<(E + 255) / 256, 256, 0, stream>>>(dstp, cnt, E);
  scan_kernel<<<1, 1024, 0, stream>>>(cnt, offs, cursor, N);
  scatter_kernel<<<(E + 255) / 256, 256, 0, stream>>>(srcp, dstp, et, cursor, packed, E);
  dim3 g(mtiles, NB);
  gemm_kernel<<<g, 256, 0, stream>>>(xb, WcatT, biascat, Y, N, ncol);
  agg_kernel<<<(N + 3) / 4, 256, 0, stream>>>(Y, offs, packed, out, N, T, 1.0f / (float)T, ncol);
}

// Round 2
// 336.374 us; speedup vs baseline: 1.3499x; 1.3499x over previous
//
#include <hip/hip_runtime.h>

typedef unsigned short u16;
typedef unsigned int u32;
typedef __attribute__((ext_vector_type(8))) short bf16x8;
typedef __attribute__((ext_vector_type(4))) float f32x4;
typedef __attribute__((ext_vector_type(2))) float f32x2;
typedef __attribute__((ext_vector_type(8))) u16 u16x8;
typedef __attribute__((ext_vector_type(4))) u16 u16x4;
typedef __attribute__((ext_vector_type(2))) u16 u16x2;
typedef __attribute__((ext_vector_type(2))) u32 u32x2;

#define DIM 128
#define AS1C(p) ((const __attribute__((address_space(1))) void*)(p))
#define AS3P(p) ((__attribute__((address_space(3))) void*)(p))

__device__ __forceinline__ u32 f2bf(float f){
  u32 x = __float_as_uint(f);
  return (x + 0x7fffu + ((x >> 16) & 1u)) >> 16;
}
__device__ __forceinline__ float bf2f(u16 u){
  return __uint_as_float(((u32)u) << 16);
}

// ---------------- prep: cast x -> bf16, zero-pad to tile rows ----------------
__global__ __launch_bounds__(256) void cast_x_kernel(const float* __restrict__ x,
                                                     u16* __restrict__ xb, int N, int rows){
  int id = blockIdx.x * 256 + threadIdx.x;
  int total4 = rows * (DIM / 4);
  if (id >= total4) return;
  int el = id * 4;
  int node = el >> 7;
  u32x2 pk;
  if (node < N){
    f32x4 v = *(const f32x4*)(x + el);
    pk.x = f2bf(v.x) | (f2bf(v.y) << 16);
    pk.y = f2bf(v.z) | (f2bf(v.w) << 16);
  } else { pk.x = 0u; pk.y = 0u; }
  *(u32x2*)(xb + el) = pk;
}

// ---------------- prep: build transposed concat weights (bf16) + bias --------
// Column layout (global col c, ncol = (3T+1)*128):
//   c in [0, 2T*128): per type t (256 cols each): even -> Wq[t][:,j], odd -> Wv[t][:,j]
//   c in [2T*128, 3T*128): k blocks: Wk[t][:,j]
//   c in [3T*128, ...): mean_t Ws[t][:,j]
__global__ __launch_bounds__(256) void build_w_kernel(
    const float* __restrict__ Wk, const float* __restrict__ bk,
    const float* __restrict__ Wq, const float* __restrict__ bq,
    const float* __restrict__ Wv, const float* __restrict__ bv,
    const float* __restrict__ Ws, const float* __restrict__ bb,
    u16* __restrict__ WcatT, float* __restrict__ biascat, int T){
  int id = blockIdx.x * 256 + threadIdx.x;
  int total = (3 * T + 1) * DIM * DIM;
  if (id >= total) return;
  int kk = id & (DIM - 1);
  int c  = id >> 7;
  int qvspan = 2 * T * DIM;
  float wv, bvv;
  if (c < qvspan){
    int t = c >> 8;
    int w = c & 255;
    int j = w >> 1;
    if ((w & 1) == 0){ wv = Wq[(t*DIM + kk)*DIM + j]; bvv = bq[t*DIM + j]; }
    else             { wv = Wv[(t*DIM + kk)*DIM + j]; bvv = bv[t*DIM + j]; }
  } else if (c < qvspan + T * DIM){
    int t = (c - qvspan) >> 7;
    int j = (c - qvspan) & (DIM - 1);
    wv = Wk[(t*DIM + kk)*DIM + j]; bvv = bk[t*DIM + j];
  } else {
    int j = c - 3 * T * DIM;
    float s = 0.f, sb = 0.f;
    for (int t = 0; t < T; ++t){ s += Ws[(t*DIM + kk)*DIM + j]; sb += bb[t*DIM + j]; }
    wv = s / (float)T; bvv = sb / (float)T;
  }
  WcatT[(size_t)c * DIM + kk] = (u16)f2bf(wv);
  if (kk == 0) biascat[c] = bvv;
}

// ---------------- CSR build --------------------------------------------------
__global__ __launch_bounds__(256) void hist_kernel(const int* __restrict__ dst,
                                                   int* __restrict__ cnt, int E){
  int e = blockIdx.x * 256 + threadIdx.x;
  if (e < E) atomicAdd(&cnt[dst[e]], 1);
}

// hierarchical scan: 2048 elements per block
__global__ __launch_bounds__(256) void scan1_kernel(const int* __restrict__ cnt,
                                                    int* __restrict__ offs,
                                                    int* __restrict__ bsum, int n){
  __shared__ int wsum[4];
  const int tid = threadIdx.x;
  const int lane = tid & 63, wave = tid >> 6;
  const int base = blockIdx.x * 2048 + tid * 8;
  int v[8]; int tot = 0;
#pragma unroll
  for (int j = 0; j < 8; ++j){
    int idx = base + j;
    int val = (idx < n) ? cnt[idx] : 0;
    v[j] = val; tot += val;
  }
  int incl = tot;
#pragma unroll
  for (int d = 1; d < 64; d <<= 1){
    int u = __shfl_up(incl, d, 64);
    if (lane >= d) incl += u;
  }
  if (lane == 63) wsum[wave] = incl;
  __syncthreads();
  int wbase = 0;
#pragma unroll
  for (int w = 0; w < 4; ++w) if (w < wave) wbase += wsum[w];
  int excl = wbase + incl - tot;
  if (tid == 255) bsum[blockIdx.x] = wbase + incl;
#pragma unroll
  for (int j = 0; j < 8; ++j){
    int idx = base + j;
    if (idx < n) offs[idx] = excl;
    excl += v[j];
  }
}

__global__ __launch_bounds__(64) void scan2_kernel(const int* __restrict__ bsum,
                                                   int* __restrict__ boffs,
                                                   int nb, int* __restrict__ offs, int n){
  int lane = threadIdx.x;
  int v = (lane < nb) ? bsum[lane] : 0;
  int incl = v;
#pragma unroll
  for (int d = 1; d < 64; d <<= 1){
    int u = __shfl_up(incl, d, 64);
    if (lane >= d) incl += u;
  }
  if (lane < nb) boffs[lane] = incl - v;
  if (lane == 63) offs[n] = incl;   // total = E
}

__global__ __launch_bounds__(256) void scan3_kernel(int* __restrict__ offs,
                                                    int* __restrict__ cursor,
                                                    const int* __restrict__ boffs, int n){
  int base = blockIdx.x * 2048 + threadIdx.x * 8;
  int add = boffs[blockIdx.x];
#pragma unroll
  for (int j = 0; j < 8; ++j){
    int idx = base + j;
    if (idx < n){
      int o = offs[idx] + add;
      offs[idx] = o;
      cursor[idx] = o;
    }
  }
}

__global__ __launch_bounds__(256) void scatter_kernel(const int* __restrict__ src,
                                                      const int* __restrict__ dst,
                                                      const int* __restrict__ et,
                                                      int* __restrict__ cursor,
                                                      int* __restrict__ packed, int E){
  int e = blockIdx.x * 256 + threadIdx.x;
  if (e >= E) return;
  int d = dst[e];
  int pos = atomicAdd(&cursor[d], 1);
  packed[pos] = (src[e] << 2) | (et[e] & 3);
}

// ---------------- batched MFMA GEMM: Y = xb @ Wcat + bias (bf16 out) ---------
// m97 pattern: global_load_lds width 16, unpadded stride-64 LDS tiles.
// D[n][m] via mfma(A=W^T fragment, B=x fragment):
//   C/D: col(=m) = lane&15, row(=n) = (lane>>4)*4 + reg
#define BK 64
__global__ __launch_bounds__(256) void gemm_kernel(const u16* __restrict__ xb,
                                                   const u16* __restrict__ WcatT,
                                                   const float* __restrict__ biascat,
                                                   u16* __restrict__ Y,
                                                   int N, int ncol){
  __shared__ u16 xt[128 * BK];
  __shared__ u16 wt[128 * BK];
  const int m0 = blockIdx.x * 128;
  const int n0 = blockIdx.y * 128;
  const int tid  = threadIdx.x;
  const int wave = tid >> 6;
  const int lane = tid & 63;
  const int l15  = lane & 15;
  const int quad = lane >> 4;
  const int wrow = wave * 32;

  f32x4 acc[2][8];
#pragma unroll
  for (int mt = 0; mt < 2; ++mt)
#pragma unroll
    for (int nt = 0; nt < 8; ++nt)
      acc[mt][nt] = (f32x4){0.f, 0.f, 0.f, 0.f};

  for (int kb = 0; kb < 2; ++kb){
    const int koff = kb * 64;
#pragma unroll
    for (int it = 0; it < 4; ++it){
      int idx = it * 256 + tid;
      int r  = idx >> 3;
      int c8 = (idx & 7) * 8;
      // wave-uniform LDS base (elements): 8 per lane-slot
      int lbase = (it * 256 + wave * 64) * 8;
      __builtin_amdgcn_global_load_lds(AS1C(xb + (size_t)(m0 + r) * DIM + koff + c8),
                                       AS3P(xt + lbase), 16, 0, 0);
      __builtin_amdgcn_global_load_lds(AS1C(WcatT + (size_t)(n0 + r) * DIM + koff + c8),
                                       AS3P(wt + lbase), 16, 0, 0);
    }
    __syncthreads();
#pragma unroll
    for (int ks = 0; ks < 2; ++ks){
      const int kbase = ks * 32 + quad * 8;
      bf16x8 bfr[2], afr[8];
#pragma unroll
      for (int mt = 0; mt < 2; ++mt)
        bfr[mt] = *(const bf16x8*)&xt[(wrow + mt * 16 + l15) * BK + kbase];
#pragma unroll
      for (int nt = 0; nt < 8; ++nt)
        afr[nt] = *(const bf16x8*)&wt[(nt * 16 + l15) * BK + kbase];
#pragma unroll
      for (int nt = 0; nt < 8; ++nt)
#pragma unroll
        for (int mt = 0; mt < 2; ++mt)
          acc[mt][nt] = __builtin_amdgcn_mfma_f32_16x16x32_bf16(afr[nt], bfr[mt], acc[mt][nt], 0, 0, 0);
    }
    __syncthreads();
  }

#pragma unroll
  for (int mt = 0; mt < 2; ++mt){
    int node = m0 + wrow + mt * 16 + l15;
    if (node >= N) continue;
    size_t rowbase = (size_t)node * ncol;
#pragma unroll
    for (int nt = 0; nt < 8; ++nt){
      int feat = n0 + nt * 16 + quad * 4;
      f32x4 b4 = *(const f32x4*)&biascat[feat];
      f32x4 v  = acc[mt][nt];
      u32 lo = f2bf(v.x + b4.x) | (f2bf(v.y + b4.y) << 16);
      u32 hi = f2bf(v.z + b4.z) | (f2bf(v.w + b4.w) << 16);
      u32x2 pk = {lo, hi};
      *(u32x2*)&Y[rowbase + feat] = pk;
    }
  }
}

// ---------------- aggregate + epilogue: one wave per dst node ----------------
// unrolled by 4: 4 independent 512B gathers in flight per iteration
__device__ __forceinline__ void edge_step(const u16* __restrict__ Y, int ncol, int lane,
                                          int p,
                                          float k0a, float k0b, float k1a, float k1b,
                                          float k2a, float k2b, float k3a, float k3b,
                                          float& acc0, float& acc1){
  int src = p >> 2;
  int t = p & 3;
  u16x4 qv = *(const u16x4*)(Y + (size_t)src * ncol + t * 256 + lane * 4);
  float ka = (t == 0) ? k0a : (t == 1) ? k1a : (t == 2) ? k2a : k3a;
  float kb = (t == 0) ? k0b : (t == 1) ? k1b : (t == 2) ? k2b : k3b;
  float q0 = bf2f(qv.x), v0 = bf2f(qv.y);
  float q1 = bf2f(qv.z), v1 = bf2f(qv.w);
  acc0 += v0 * __builtin_amdgcn_rcpf(1.f + __expf(-(ka + q0)));
  acc1 += v1 * __builtin_amdgcn_rcpf(1.f + __expf(-(kb + q1)));
}

__global__ __launch_bounds__(256) void agg_kernel(const u16* __restrict__ Y,
                                                  const int* __restrict__ offs,
                                                  const int* __restrict__ packed,
                                                  float* __restrict__ out,
                                                  int N, int T, float invT, int ncol){
  const int wave = threadIdx.x >> 6;
  const int lane = threadIdx.x & 63;
  const int i = blockIdx.x * 4 + wave;
  if (i >= N) return;

  const int kqoff = 2 * T * DIM;   // 1024
  const int soff  = 3 * T * DIM;   // 1536
  const u16* yr = Y + (size_t)i * ncol;
  const int c2 = lane * 2;

  u16x2 kw0 = *(const u16x2*)(yr + kqoff + 0 * DIM + c2);
  u16x2 kw1 = *(const u16x2*)(yr + kqoff + 1 * DIM + c2);
  u16x2 kw2 = *(const u16x2*)(yr + kqoff + 2 * DIM + c2);
  u16x2 kw3 = *(const u16x2*)(yr + kqoff + 3 * DIM + c2);
  float k0a = bf2f(kw0.x), k0b = bf2f(kw0.y);
  float k1a = bf2f(kw1.x), k1b = bf2f(kw1.y);
  float k2a = bf2f(kw2.x), k2b = bf2f(kw2.y);
  float k3a = bf2f(kw3.x), k3b = bf2f(kw3.y);
  u16x2 sw = *(const u16x2*)(yr + soff + c2);
  float s0 = bf2f(sw.x), s1 = bf2f(sw.y);

  float acc0 = 0.f, acc1 = 0.f;
  int e = offs[i], end = offs[i + 1];
  for (; e + 4 <= end; e += 4){
    int p0 = __builtin_amdgcn_readfirstlane(packed[e]);
    int p1 = __builtin_amdgcn_readfirstlane(packed[e + 1]);
    int p2 = __builtin_amdgcn_readfirstlane(packed[e + 2]);
    int p3 = __builtin_amdgcn_readfirstlane(packed[e + 3]);
    // 4 independent gathers — compiler hoists loads ahead of compute
    int s0i = p0 >> 2, s1i = p1 >> 2, s2i = p2 >> 2, s3i = p3 >> 2;
    u16x4 a0 = *(const u16x4*)(Y + (size_t)s0i * ncol + (p0 & 3) * 256 + lane * 4);
    u16x4 a1 = *(const u16x4*)(Y + (size_t)s1i * ncol + (p1 & 3) * 256 + lane * 4);
    u16x4 a2 = *(const u16x4*)(Y + (size_t)s2i * ncol + (p2 & 3) * 256 + lane * 4);
    u16x4 a3 = *(const u16x4*)(Y + (size_t)s3i * ncol + (p3 & 3) * 256 + lane * 4);
    {
      int t = p0 & 3;
      float ka = (t == 0) ? k0a : (t == 1) ? k1a : (t == 2) ? k2a : k3a;
      float kb = (t == 0) ? k0b : (t == 1) ? k1b : (t == 2) ? k2b : k3b;
      acc0 += bf2f(a0.y) * __builtin_amdgcn_rcpf(1.f + __expf(-(ka + bf2f(a0.x))));
      acc1 += bf2f(a0.w) * __builtin_amdgcn_rcpf(1.f + __expf(-(kb + bf2f(a0.z))));
    }
    {
      int t = p1 & 3;
      float ka = (t == 0) ? k0a : (t == 1) ? k1a : (t == 2) ? k2a : k3a;
      float kb = (t == 0) ? k0b : (t == 1) ? k1b : (t == 2) ? k2b : k3b;
      acc0 += bf2f(a1.y) * __builtin_amdgcn_rcpf(1.f + __expf(-(ka + bf2f(a1.x))));
      acc1 += bf2f(a1.w) * __builtin_amdgcn_rcpf(1.f + __expf(-(kb + bf2f(a1.z))));
    }
    {
      int t = p2 & 3;
      float ka = (t == 0) ? k0a : (t == 1) ? k1a : (t == 2) ? k2a : k3a;
      float kb = (t == 0) ? k0b : (t == 1) ? k1b : (t == 2) ? k2b : k3b;
      acc0 += bf2f(a2.y) * __builtin_amdgcn_rcpf(1.f + __expf(-(ka + bf2f(a2.x))));
      acc1 += bf2f(a2.w) * __builtin_amdgcn_rcpf(1.f + __expf(-(kb + bf2f(a2.z))));
    }
    {
      int t = p3 & 3;
      float ka = (t == 0) ? k0a : (t == 1) ? k1a : (t == 2) ? k2a : k3a;
      float kb = (t == 0) ? k0b : (t == 1) ? k1b : (t == 2) ? k2b : k3b;
      acc0 += bf2f(a3.y) * __builtin_amdgcn_rcpf(1.f + __expf(-(ka + bf2f(a3.x))));
      acc1 += bf2f(a3.w) * __builtin_amdgcn_rcpf(1.f + __expf(-(kb + bf2f(a3.z))));
    }
  }
  for (; e < end; ++e){
    int p = __builtin_amdgcn_readfirstlane(packed[e]);
    edge_step(Y, ncol, lane, p, k0a, k0b, k1a, k1b, k2a, k2b, k3a, k3b, acc0, acc1);
  }
  f32x2 o = { invT * acc0 + s0, invT * acc1 + s1 };
  *(f32x2*)&out[(size_t)i * DIM + c2] = o;
}

// ---------------- launch -----------------------------------------------------
extern "C" void kernel_launch(void* const* d_in, const int* in_sizes, int n_in,
                              void* d_out, int out_size, void* d_ws, size_t ws_size,
                              hipStream_t stream){
  const float* x  = (const float*)d_in[0];
  const int*   ei = (const int*)d_in[1];
  const int*   et = (const int*)d_in[2];
  const float* Wk = (const float*)d_in[3];
  const float* bk = (const float*)d_in[4];
  const float* Wq = (const float*)d_in[5];
  const float* bq = (const float*)d_in[6];
  const float* Wv = (const float*)d_in[7];
  const float* bv = (const float*)d_in[8];
  const float* Ws = (const float*)d_in[9];
  const float* bb = (const float*)d_in[10];
  float* out = (float*)d_out;

  const int N = in_sizes[0] / DIM;
  const int E = in_sizes[2];
  const int T = in_sizes[3] / (DIM * DIM);
  const int NB = 3 * T + 1;
  const int ncol = NB * DIM;
  const int mtiles = (N + 127) / 128;
  const int rows = mtiles * 128;
  const int nscan = (N + 2047) / 2048;

  char* ws = (char*)d_ws;
  size_t off = 0;
  auto alloc = [&](size_t bytes) -> char* {
    char* p = ws + off;
    off = (off + bytes + 255) & ~(size_t)255;
    return p;
  };
  u16*   xb      = (u16*)alloc((size_t)rows * DIM * 2);
  u16*   WcatT   = (u16*)alloc((size_t)ncol * DIM * 2);
  float* biascat = (float*)alloc((size_t)ncol * 4);
  u16*   Y       = (u16*)alloc((size_t)N * ncol * 2);
  int*   cnt     = (int*)alloc((size_t)N * 4);
  int*   offs    = (int*)alloc((size_t)(N + 1) * 4);
  int*   cursor  = (int*)alloc((size_t)N * 4);
  int*   packed  = (int*)alloc((size_t)E * 4);
  int*   bsum    = (int*)alloc((size_t)nscan * 4);
  int*   boffs   = (int*)alloc((size_t)nscan * 4);
  (void)ws_size; (void)n_in; (void)out_size;

  const int* srcp = ei;
  const int* dstp = ei + E;

  hipMemsetAsync(cnt, 0, (size_t)N * 4, stream);
  cast_x_kernel<<<(rows * (DIM / 4) + 255) / 256, 256, 0, stream>>>(x, xb, N, rows);
  build_w_kernel<<<(ncol * DIM + 255) / 256, 256, 0, stream>>>(Wk, bk, Wq, bq, Wv, bv, Ws, bb, WcatT, biascat, T);
  hist_kernel<<<(E + 255) / 256, 256, 0, stream>>>(dstp, cnt, E);
  scan1_kernel<<<nscan, 256, 0, stream>>>(cnt, offs, bsum, N);
  scan2_kernel<<<1, 64, 0, stream>>>(bsum, boffs, nscan, offs, N);
  scan3_kernel<<<nscan, 256, 0, stream>>>(offs, cursor, boffs, N);
  scatter_kernel<<<(E + 255) / 256, 256, 0, stream>>>(srcp, dstp, et, cursor, packed, E);
  dim3 g(mtiles, NB);
  gemm_kernel<<<g, 256, 0, stream>>>(xb, WcatT, biascat, Y, N, ncol);
  agg_kernel<<<(N + 3) / 4, 256, 0, stream>>>(Y, offs, packed, out, N, T, 1.0f / (float)T, ncol);
}

// Round 3
// 311.595 us; speedup vs baseline: 1.4572x; 1.0795x over previous
//
#include <hip/hip_runtime.h>

typedef unsigned short u16;
typedef unsigned int u32;
typedef __attribute__((ext_vector_type(8))) short bf16x8;
typedef __attribute__((ext_vector_type(4))) float f32x4;
typedef __attribute__((ext_vector_type(2))) float f32x2;
typedef __attribute__((ext_vector_type(8))) u16 u16x8;
typedef __attribute__((ext_vector_type(4))) u16 u16x4;
typedef __attribute__((ext_vector_type(2))) u16 u16x2;
typedef __attribute__((ext_vector_type(2))) u32 u32x2;

#define DIM 128
#define AS1C(p) ((const __attribute__((address_space(1))) void*)(p))
#define AS3P(p) ((__attribute__((address_space(3))) void*)(p))

__device__ __forceinline__ u32 f2bf(float f){
  u32 x = __float_as_uint(f);
  return (x + 0x7fffu + ((x >> 16) & 1u)) >> 16;
}
__device__ __forceinline__ float bf2f(u16 u){
  return __uint_as_float(((u32)u) << 16);
}

// ---------------- prep: cast x -> bf16, zero-pad to tile rows ----------------
__global__ __launch_bounds__(256) void cast_x_kernel(const float* __restrict__ x,
                                                     u16* __restrict__ xb, int N, int rows){
  int id = blockIdx.x * 256 + threadIdx.x;
  int total4 = rows * (DIM / 4);
  if (id >= total4) return;
  int el = id * 4;
  int node = el >> 7;
  u32x2 pk;
  if (node < N){
    f32x4 v = *(const f32x4*)(x + el);
    pk.x = f2bf(v.x) | (f2bf(v.y) << 16);
    pk.y = f2bf(v.z) | (f2bf(v.w) << 16);
  } else { pk.x = 0u; pk.y = 0u; }
  *(u32x2*)(xb + el) = pk;
}

// ---------------- prep: build transposed concat weights (bf16) + bias --------
// Column layout (global col c, ncol = (3T+1)*128):
//   c in [0, 2T*128): per type t (256 cols each): even -> Wq[t][:,j], odd -> Wv[t][:,j]
//   c in [2T*128, 3T*128): k blocks: Wk[t][:,j]
//   c in [3T*128, ...): mean_t Ws[t][:,j]
__global__ __launch_bounds__(256) void build_w_kernel(
    const float* __restrict__ Wk, const float* __restrict__ bk,
    const float* __restrict__ Wq, const float* __restrict__ bq,
    const float* __restrict__ Wv, const float* __restrict__ bv,
    const float* __restrict__ Ws, const float* __restrict__ bb,
    u16* __restrict__ WcatT, float* __restrict__ biascat, int T){
  int id = blockIdx.x * 256 + threadIdx.x;
  int total = (3 * T + 1) * DIM * DIM;
  if (id >= total) return;
  int kk = id & (DIM - 1);
  int c  = id >> 7;
  int qvspan = 2 * T * DIM;
  float wv, bvv;
  if (c < qvspan){
    int t = c >> 8;
    int w = c & 255;
    int j = w >> 1;
    if ((w & 1) == 0){ wv = Wq[(t*DIM + kk)*DIM + j]; bvv = bq[t*DIM + j]; }
    else             { wv = Wv[(t*DIM + kk)*DIM + j]; bvv = bv[t*DIM + j]; }
  } else if (c < qvspan + T * DIM){
    int t = (c - qvspan) >> 7;
    int j = (c - qvspan) & (DIM - 1);
    wv = Wk[(t*DIM + kk)*DIM + j]; bvv = bk[t*DIM + j];
  } else {
    int j = c - 3 * T * DIM;
    float s = 0.f, sb = 0.f;
    for (int t = 0; t < T; ++t){ s += Ws[(t*DIM + kk)*DIM + j]; sb += bb[t*DIM + j]; }
    wv = s / (float)T; bvv = sb / (float)T;
  }
  WcatT[(size_t)c * DIM + kk] = (u16)f2bf(wv);
  if (kk == 0) biascat[c] = bvv;
}

// ---------------- CSR build --------------------------------------------------
// hist also records each edge's rank within its dst bucket (atomic return val)
__global__ __launch_bounds__(256) void hist_kernel(const int* __restrict__ dst,
                                                   int* __restrict__ cnt,
                                                   int* __restrict__ rank, int E){
  int e = blockIdx.x * 256 + threadIdx.x;
  if (e < E) rank[e] = atomicAdd(&cnt[dst[e]], 1);
}

// hierarchical scan: 2048 elements per block
__global__ __launch_bounds__(256) void scan1_kernel(const int* __restrict__ cnt,
                                                    int* __restrict__ offs,
                                                    int* __restrict__ bsum, int n){
  __shared__ int wsum[4];
  const int tid = threadIdx.x;
  const int lane = tid & 63, wave = tid >> 6;
  const int base = blockIdx.x * 2048 + tid * 8;
  int v[8]; int tot = 0;
#pragma unroll
  for (int j = 0; j < 8; ++j){
    int idx = base + j;
    int val = (idx < n) ? cnt[idx] : 0;
    v[j] = val; tot += val;
  }
  int incl = tot;
#pragma unroll
  for (int d = 1; d < 64; d <<= 1){
    int u = __shfl_up(incl, d, 64);
    if (lane >= d) incl += u;
  }
  if (lane == 63) wsum[wave] = incl;
  __syncthreads();
  int wbase = 0;
#pragma unroll
  for (int w = 0; w < 4; ++w) if (w < wave) wbase += wsum[w];
  int excl = wbase + incl - tot;
  if (tid == 255) bsum[blockIdx.x] = wbase + incl;
#pragma unroll
  for (int j = 0; j < 8; ++j){
    int idx = base + j;
    if (idx < n) offs[idx] = excl;
    excl += v[j];
  }
}

__global__ __launch_bounds__(64) void scan2_kernel(const int* __restrict__ bsum,
                                                   int* __restrict__ boffs,
                                                   int nb, int* __restrict__ offs, int n){
  int lane = threadIdx.x;
  int v = (lane < nb) ? bsum[lane] : 0;
  int incl = v;
#pragma unroll
  for (int d = 1; d < 64; d <<= 1){
    int u = __shfl_up(incl, d, 64);
    if (lane >= d) incl += u;
  }
  if (lane < nb) boffs[lane] = incl - v;
  if (lane == 63) offs[n] = incl;
}

__global__ __launch_bounds__(256) void scan3_kernel(int* __restrict__ offs,
                                                    const int* __restrict__ boffs, int n){
  int base = blockIdx.x * 2048 + threadIdx.x * 8;
  int add = boffs[blockIdx.x];
#pragma unroll
  for (int j = 0; j < 8; ++j){
    int idx = base + j;
    if (idx < n) offs[idx] += add;
  }
}

// no atomics: pos = offs[d] + rank[e]
__global__ __launch_bounds__(256) void scatter_kernel(const int* __restrict__ src,
                                                      const int* __restrict__ dst,
                                                      const int* __restrict__ et,
                                                      const int* __restrict__ offs,
                                                      const int* __restrict__ rank,
                                                      int* __restrict__ packed, int E){
  int e = blockIdx.x * 256 + threadIdx.x;
  if (e >= E) return;
  int pos = offs[dst[e]] + rank[e];
  packed[pos] = (src[e] << 2) | (et[e] & 3);
}

// ---------------- batched MFMA GEMM: Y = xb @ Wcat + bias (bf16 out) ---------
// global_load_lds width 16 + XOR-swizzled LDS (conflict-free ds_read_b128):
//   physical block p of row r holds logical k-block p^(r&7)
// grid: x = n-tile (13, fastest) so consecutive blocks share the same x-tile.
// D[n][m] via mfma(A=W^T fragment, B=x fragment):
//   C/D: col(=m) = lane&15, row(=n) = (lane>>4)*4 + reg
#define BK 64
__global__ __launch_bounds__(256) void gemm_kernel(const u16* __restrict__ xb,
                                                   const u16* __restrict__ WcatT,
                                                   const float* __restrict__ biascat,
                                                   u16* __restrict__ Y,
                                                   int N, int ncol){
  __shared__ u16 xt[128 * BK];
  __shared__ u16 wt[128 * BK];
  const int n0 = blockIdx.x * 128;
  const int m0 = blockIdx.y * 128;
  const int tid  = threadIdx.x;
  const int wave = tid >> 6;
  const int lane = tid & 63;
  const int l15  = lane & 15;
  const int quad = lane >> 4;
  const int wrow = wave * 32;

  f32x4 acc[2][8];
#pragma unroll
  for (int mt = 0; mt < 2; ++mt)
#pragma unroll
    for (int nt = 0; nt < 8; ++nt)
      acc[mt][nt] = (f32x4){0.f, 0.f, 0.f, 0.f};

  for (int kb = 0; kb < 2; ++kb){
    const int koff = kb * 64;
#pragma unroll
    for (int it = 0; it < 4; ++it){
      int idx = it * 256 + tid;
      int r  = idx >> 3;
      int p  = idx & 7;                  // physical 8-elem block within row
      int lb = p ^ (r & 7);              // logical k-block fetched (swizzle)
      int lbase = (it * 256 + wave * 64) * 8;   // wave-uniform LDS base (elems)
      __builtin_amdgcn_global_load_lds(AS1C(xb + (size_t)(m0 + r) * DIM + koff + lb * 8),
                                       AS3P(xt + lbase), 16, 0, 0);
      __builtin_amdgcn_global_load_lds(AS1C(WcatT + (size_t)(n0 + r) * DIM + koff + lb * 8),
                                       AS3P(wt + lbase), 16, 0, 0);
    }
    __syncthreads();
#pragma unroll
    for (int ks = 0; ks < 2; ++ks){
      // logical block B = ks*4+quad -> physical column offset within row
      const int cb = ((ks * 4 + quad) ^ (l15 & 7)) * 8;
      bf16x8 bfr[2], afr[8];
#pragma unroll
      for (int mt = 0; mt < 2; ++mt)
        bfr[mt] = *(const bf16x8*)&xt[(wrow + mt * 16 + l15) * BK + cb];
#pragma unroll
      for (int nt = 0; nt < 8; ++nt)
        afr[nt] = *(const bf16x8*)&wt[(nt * 16 + l15) * BK + cb];
#pragma unroll
      for (int nt = 0; nt < 8; ++nt)
#pragma unroll
        for (int mt = 0; mt < 2; ++mt)
          acc[mt][nt] = __builtin_amdgcn_mfma_f32_16x16x32_bf16(afr[nt], bfr[mt], acc[mt][nt], 0, 0, 0);
    }
    __syncthreads();
  }

#pragma unroll
  for (int mt = 0; mt < 2; ++mt){
    int node = m0 + wrow + mt * 16 + l15;
    if (node >= N) continue;
    size_t rowbase = (size_t)node * ncol;
#pragma unroll
    for (int nt = 0; nt < 8; ++nt){
      int feat = n0 + nt * 16 + quad * 4;
      f32x4 b4 = *(const f32x4*)&biascat[feat];
      f32x4 v  = acc[mt][nt];
      u32 lo = f2bf(v.x + b4.x) | (f2bf(v.y + b4.y) << 16);
      u32 hi = f2bf(v.z + b4.z) | (f2bf(v.w + b4.w) << 16);
      u32x2 pk = {lo, hi};
      *(u32x2*)&Y[rowbase + feat] = pk;
    }
  }
}

// ---------------- aggregate + epilogue: one wave per dst node ----------------
// unrolled by 8: 8 independent 512B gathers in flight per iteration
__global__ __launch_bounds__(256) void agg_kernel(const u16* __restrict__ Y,
                                                  const int* __restrict__ offs,
                                                  const int* __restrict__ packed,
                                                  float* __restrict__ out,
                                                  int N, int T, float invT, int ncol){
  const int wave = threadIdx.x >> 6;
  const int lane = threadIdx.x & 63;
  const int i = blockIdx.x * 4 + wave;
  if (i >= N) return;

  const int kqoff = 2 * T * DIM;   // 1024
  const int soff  = 3 * T * DIM;   // 1536
  const u16* yr = Y + (size_t)i * ncol;
  const int c2 = lane * 2;

  u16x2 kw0 = *(const u16x2*)(yr + kqoff + 0 * DIM + c2);
  u16x2 kw1 = *(const u16x2*)(yr + kqoff + 1 * DIM + c2);
  u16x2 kw2 = *(const u16x2*)(yr + kqoff + 2 * DIM + c2);
  u16x2 kw3 = *(const u16x2*)(yr + kqoff + 3 * DIM + c2);
  float ka[4] = { bf2f(kw0.x), bf2f(kw1.x), bf2f(kw2.x), bf2f(kw3.x) };
  float kb[4] = { bf2f(kw0.y), bf2f(kw1.y), bf2f(kw2.y), bf2f(kw3.y) };
  u16x2 sw = *(const u16x2*)(yr + soff + c2);
  float s0 = bf2f(sw.x), s1 = bf2f(sw.y);

  float acc0 = 0.f, acc1 = 0.f;
  int e = offs[i], end = offs[i + 1];
  for (; e + 8 <= end; e += 8){
    int p[8];
#pragma unroll
    for (int j = 0; j < 8; ++j)
      p[j] = __builtin_amdgcn_readfirstlane(packed[e + j]);
    u16x4 a[8];
#pragma unroll
    for (int j = 0; j < 8; ++j)
      a[j] = *(const u16x4*)(Y + (size_t)(p[j] >> 2) * ncol + (p[j] & 3) * 256 + lane * 4);
#pragma unroll
    for (int j = 0; j < 8; ++j){
      int t = p[j] & 3;
      float k0 = (t == 0) ? ka[0] : (t == 1) ? ka[1] : (t == 2) ? ka[2] : ka[3];
      float k1 = (t == 0) ? kb[0] : (t == 1) ? kb[1] : (t == 2) ? kb[2] : kb[3];
      acc0 += bf2f(a[j].y) * __builtin_amdgcn_rcpf(1.f + __expf(-(k0 + bf2f(a[j].x))));
      acc1 += bf2f(a[j].w) * __builtin_amdgcn_rcpf(1.f + __expf(-(k1 + bf2f(a[j].z))));
    }
  }
  for (; e < end; ++e){
    int p = __builtin_amdgcn_readfirstlane(packed[e]);
    int t = p & 3;
    u16x4 qv = *(const u16x4*)(Y + (size_t)(p >> 2) * ncol + t * 256 + lane * 4);
    float k0 = (t == 0) ? ka[0] : (t == 1) ? ka[1] : (t == 2) ? ka[2] : ka[3];
    float k1 = (t == 0) ? kb[0] : (t == 1) ? kb[1] : (t == 2) ? kb[2] : kb[3];
    acc0 += bf2f(qv.y) * __builtin_amdgcn_rcpf(1.f + __expf(-(k0 + bf2f(qv.x))));
    acc1 += bf2f(qv.w) * __builtin_amdgcn_rcpf(1.f + __expf(-(k1 + bf2f(qv.z))));
  }
  f32x2 o = { invT * acc0 + s0, invT * acc1 + s1 };
  *(f32x2*)&out[(size_t)i * DIM + c2] = o;
}

// ---------------- launch -----------------------------------------------------
extern "C" void kernel_launch(void* const* d_in, const int* in_sizes, int n_in,
                              void* d_out, int out_size, void* d_ws, size_t ws_size,
                              hipStream_t stream){
  const float* x  = (const float*)d_in[0];
  const int*   ei = (const int*)d_in[1];
  const int*   et = (const int*)d_in[2];
  const float* Wk = (const float*)d_in[3];
  const float* bk = (const float*)d_in[4];
  const float* Wq = (const float*)d_in[5];
  const float* bq = (const float*)d_in[6];
  const float* Wv = (const float*)d_in[7];
  const float* bv = (const float*)d_in[8];
  const float* Ws = (const float*)d_in[9];
  const float* bb = (const float*)d_in[10];
  float* out = (float*)d_out;

  const int N = in_sizes[0] / DIM;
  const int E = in_sizes[2];
  const int T = in_sizes[3] / (DIM * DIM);
  const int NB = 3 * T + 1;
  const int ncol = NB * DIM;
  const int mtiles = (N + 127) / 128;
  const int rows = mtiles * 128;
  const int nscan = (N + 2047) / 2048;

  char* ws = (char*)d_ws;
  size_t off = 0;
  auto alloc = [&](size_t bytes) -> char* {
    char* p = ws + off;
    off = (off + bytes + 255) & ~(size_t)255;
    return p;
  };
  u16*   xb      = (u16*)alloc((size_t)rows * DIM * 2);
  u16*   WcatT   = (u16*)alloc((size_t)ncol * DIM * 2);
  float* biascat = (float*)alloc((size_t)ncol * 4);
  u16*   Y       = (u16*)alloc((size_t)N * ncol * 2);
  int*   cnt     = (int*)alloc((size_t)N * 4);
  int*   offs    = (int*)alloc((size_t)(N + 1) * 4);
  int*   rank    = (int*)alloc((size_t)E * 4);
  int*   packed  = (int*)alloc((size_t)E * 4);
  int*   bsum    = (int*)alloc((size_t)nscan * 4);
  int*   boffs   = (int*)alloc((size_t)nscan * 4);
  (void)ws_size; (void)n_in; (void)out_size;

  const int* srcp = ei;
  const int* dstp = ei + E;

  hipMemsetAsync(cnt, 0, (size_t)N * 4, stream);
  cast_x_kernel<<<(rows * (DIM / 4) + 255) / 256, 256, 0, stream>>>(x, xb, N, rows);
  build_w_kernel<<<(ncol * DIM + 255) / 256, 256, 0, stream>>>(Wk, bk, Wq, bq, Wv, bv, Ws, bb, WcatT, biascat, T);
  hist_kernel<<<(E + 255) / 256, 256, 0, stream>>>(dstp, cnt, rank, E);
  scan1_kernel<<<nscan, 256, 0, stream>>>(cnt, offs, bsum, N);
  scan2_kernel<<<1, 64, 0, stream>>>(bsum, boffs, nscan, offs, N);
  scan3_kernel<<<nscan, 256, 0, stream>>>(offs, boffs, N);
  scatter_kernel<<<(E + 255) / 256, 256, 0, stream>>>(srcp, dstp, et, offs, rank, packed, E);
  dim3 g(NB, mtiles);
  gemm_kernel<<<g, 256, 0, stream>>>(xb, WcatT, biascat, Y, N, ncol);
  agg_kernel<<<(N + 3) / 4, 256, 0, stream>>>(Y, offs, packed, out, N, T, 1.0f / (float)T, ncol);
}